// Round 4
// baseline (45965.543 us; speedup 1.0000x reference)
//
#include <hip/hip_runtime.h>
#include <math.h>

// Problem constants (fixed by the reference)
#define NV 20000
#define NH 512
#define NT 1024
#define NB 32
#define MAXD 64

// LSTM persistent-kernel geometry
#define NGRP 8      // groups (independent batch-row sets), sync domain = 1 group
#define BPG 32      // blocks per group
#define BPB 4       // batch rows per group  (NB / NGRP)
#define UPB 16      // hidden units per block (NH / BPG)
#define NJ 64       // gate rows per block = 4*UPB
#define KTOT 1024   // 2*NH
#define NTH 512
#define KPT 32      // k elements per thread slice

// ws layout: [ path: NV*NH f32 | hbuf: 2*NB*NH f32 | flags: 256 ints ]  ~= 41.1 MB

__global__ void init_kernel(float* __restrict__ hbuf, int* __restrict__ flags) {
  int i = blockIdx.x * blockDim.x + threadIdx.x;
  if (i < 2 * NB * NH) hbuf[i] = 0.f;
  if (i < 256) flags[i] = 0;
}

// One block per node: all 256 threads walk the same parent chain (uniform),
// each thread accumulates 2 of the 512 embedding columns (coalesced).
__global__ __launch_bounds__(256)
void path_kernel(const int* __restrict__ parents,
                 const float* __restrict__ weight,
                 const float* __restrict__ emb,
                 float* __restrict__ path) {
  int v = blockIdx.x;
  int h = threadIdx.x;
  float acc0 = 0.f, acc1 = 0.f;
  float w = 1.f;
  int cur = v;
#pragma unroll 1
  for (int d = 0; d < MAXD; ++d) {
    if (cur < 0) break;
    const float* row = emb + (size_t)cur * NH;
    acc0 = fmaf(w, row[h], acc0);
    acc1 = fmaf(w, row[h + 256], acc1);
    w *= weight[cur];
    cur = parents[cur];
  }
  path[(size_t)v * NH + h] = acc0;
  path[(size_t)v * NH + h + 256] = acc1;
}

// Persistent LSTM: 256 blocks = 8 groups x 32 blocks.
// Cross-block communication (hbuf, flags) uses per-access system-scope
// atomics (sc0 sc1: write-through / cache-bypass to the coherent point).
// NO cache-wide fences -> path/gate_w/ev stay L2-resident across steps.
// Producer ordering: wave-0 h-stores -> s_waitcnt vmcnt(0) -> flag add.
__global__
void lstm_kernel(const int* __restrict__ ev,
                 const float* __restrict__ path,
                 const float* __restrict__ gate_w,
                 const float* __restrict__ gate_b,
                 float* __restrict__ hbuf,   // [2][NB][NH]
                 int* __restrict__ flags,    // per-group monotonic barrier ctr
                 float* __restrict__ out) {  // [3][NT][NB][NH]
  // in_s padded with one extra float per 32 (f(k)=k+(k>>5)) -> conflict-free
  __shared__ float in_s[BPB][KTOT + KTOT / 32];
  __shared__ float p_s[KPT][NJ * BPB + 1];   // stride 257 -> conflict-free
  __shared__ float zred[NJ * BPB];
  __shared__ float c_s[BPB][UPB];

  const int bid = blockIdx.x;
  const int grp = bid & 7;
  const int blk = bid >> 3;
  const int b0 = grp * BPB;
  const int u0 = blk * UPB;
  const int tid = threadIdx.x;
  const int jg = tid >> 5;   // 0..15: which 4-row group
  const int ks = tid & 31;   // 0..31: which 32-wide k slice

  // Load this thread's gate_w slice into registers (reused for all 1024 steps).
  float w[4][KPT];
#pragma unroll
  for (int jj = 0; jj < 4; ++jj) {
    int r = jg * 4 + jj;                        // 0..63: gate*16 + uu
    int j = (r >> 4) * NH + u0 + (r & 15);      // global gate row
    const float* wr = gate_w + (size_t)j * KTOT + ks * KPT;
#pragma unroll
    for (int kk = 0; kk < KPT; ++kk) w[jj][kk] = wr[kk];
  }

  if (tid < BPB * UPB) c_s[tid >> 4][tid & 15] = 0.f;

  const int sb = tid >> 7;     // staging: batch row
  const int seg = tid & 127;   // staging: 8-float chunk within [x|h]
  const int c0 = seg * 8;
  int* flagp = &flags[grp * 32];
  const size_t plane = (size_t)NT * NB * NH;

  // ---- pre-stage x(0) (path gather), seg<64 covers the x half ----
  if (seg < 64) {
    int e = ev[0 * NB + b0 + sb];
    const float* src = path + (size_t)e * NH + c0;
    float4 v0 = *(const float4*)(src);
    float4 v1 = *(const float4*)(src + 4);
    float* dst = &in_s[sb][0];
    int f0 = c0 + (c0 >> 5);
    dst[f0 + 0] = v0.x; dst[f0 + 1] = v0.y; dst[f0 + 2] = v0.z; dst[f0 + 3] = v0.w;
    dst[f0 + 4] = v1.x; dst[f0 + 5] = v1.y; dst[f0 + 6] = v1.z; dst[f0 + 7] = v1.w;
  }

#pragma unroll 1
  for (int t = 0; t < NT; ++t) {
    const bool more = (t + 1 < NT);

    // ---- stage h(t) for this group's 4 batch rows (coherent bypass loads) --
    if (seg >= 64) {
      const float* hsrc = hbuf + ((size_t)(t & 1) * NB + (b0 + sb)) * NH + (c0 - NH);
      float hv8[8];
#pragma unroll
      for (int q = 0; q < 8; ++q)
        hv8[q] = __hip_atomic_load(hsrc + q, __ATOMIC_RELAXED, __HIP_MEMORY_SCOPE_SYSTEM);
      float* dst = &in_s[sb][0];
      int f0 = c0 + (c0 >> 5);
#pragma unroll
      for (int q = 0; q < 8; ++q) dst[f0 + q] = hv8[q];
    }
    __syncthreads();   // A: in_s(t) complete

    // ---- partial GEMM: acc[jj][bi] over this thread's 32-k slice ----
    float acc[4][BPB];
#pragma unroll
    for (int jj = 0; jj < 4; ++jj)
#pragma unroll
      for (int bi = 0; bi < BPB; ++bi) acc[jj][bi] = 0.f;
    const int fb = ks * (KPT + 1);  // f(ks*32) = ks*33
#pragma unroll
    for (int bi = 0; bi < BPB; ++bi) {
      const float* inp = &in_s[bi][fb];
#pragma unroll
      for (int kk = 0; kk < KPT; ++kk) {
        float x = inp[kk];
        acc[0][bi] = fmaf(w[0][kk], x, acc[0][bi]);
        acc[1][bi] = fmaf(w[1][kk], x, acc[1][bi]);
        acc[2][bi] = fmaf(w[2][kk], x, acc[2][bi]);
        acc[3][bi] = fmaf(w[3][kk], x, acc[3][bi]);
      }
    }
#pragma unroll
    for (int jj = 0; jj < 4; ++jj) {
      int r = jg * 4 + jj;
#pragma unroll
      for (int bi = 0; bi < BPB; ++bi)
        p_s[ks][r * BPB + bi] = acc[jj][bi];
    }
    __syncthreads();   // B: p_s complete; in_s dead

    // ---- prefetch x(t+1) into in_s x-half (barrier-independent) ----
    if (more && seg < 64) {
      int e = ev[(t + 1) * NB + b0 + sb];
      const float* src = path + (size_t)e * NH + c0;
      float4 v0 = *(const float4*)(src);
      float4 v1 = *(const float4*)(src + 4);
      float* dst = &in_s[sb][0];
      int f0 = c0 + (c0 >> 5);
      dst[f0 + 0] = v0.x; dst[f0 + 1] = v0.y; dst[f0 + 2] = v0.z; dst[f0 + 3] = v0.w;
      dst[f0 + 4] = v1.x; dst[f0 + 5] = v1.y; dst[f0 + 6] = v1.z; dst[f0 + 7] = v1.w;
    }

    // ---- reduce k-slices + bias ----
    if (tid < NJ * BPB) {
      float s = 0.f;
#pragma unroll
      for (int k2 = 0; k2 < KPT; ++k2) s += p_s[k2][tid];
      int r = tid >> 2;
      s += gate_b[(r >> 4) * NH + u0 + (r & 15)];
      zred[tid] = s;
    }
    __syncthreads();   // C: zred complete

    // ---- gates + state update (wave 0 only: tid < 64) ----
    float hv = 0.f, cv = 0.f, ogv = 0.f;
    int b = 0, u = 0;
    const bool gate_thread = tid < BPB * UPB;
    if (gate_thread) {
      int bi = tid >> 4, uu = tid & 15;
      float zi = zred[(uu) * BPB + bi];
      float zf = zred[(UPB + uu) * BPB + bi];
      float zg = zred[(2 * UPB + uu) * BPB + bi];
      float zo = zred[(3 * UPB + uu) * BPB + bi];
      float ig = 1.f / (1.f + expf(-zi));
      float fg = 1.f / (1.f + expf(-zf));
      float gg = tanhf(zg);
      ogv = 1.f / (1.f + expf(-zo));
      cv = fmaf(fg, c_s[bi][uu], ig * gg);
      hv = ogv * tanhf(cv);
      c_s[bi][uu] = cv;
      b = b0 + bi; u = u0 + uu;
      if (more) {
        float* hdst = hbuf + ((size_t)((t + 1) & 1) * NB + b) * NH + u;
        __hip_atomic_store(hdst, hv, __ATOMIC_RELAXED, __HIP_MEMORY_SCOPE_SYSTEM);
      }
    }

    // ---- arrive: wave-local wait for h-store completion, then one add ----
    if (more && tid == 0) {
      asm volatile("s_waitcnt vmcnt(0)" ::: "memory");
      __hip_atomic_fetch_add(flagp, 1, __ATOMIC_RELAXED, __HIP_MEMORY_SCOPE_SYSTEM);
    }

    // ---- output stores overlap the barrier wait window ----
    if (gate_thread) {
      size_t o0 = ((size_t)t * NB + b) * NH + u;
      out[o0] = hv;
      out[plane + o0] = cv;
      out[2 * plane + o0] = ogv;
    }

    // ---- single-lane poll ----
    if (more && tid == 0) {
      const int target = BPG * (t + 1);
      while (__hip_atomic_load(flagp, __ATOMIC_RELAXED, __HIP_MEMORY_SCOPE_SYSTEM) < target)
        __builtin_amdgcn_s_sleep(2);
    }
    __syncthreads();   // E: all waves released; h(t+1) globally visible
  }
}

extern "C" void kernel_launch(void* const* d_in, const int* in_sizes, int n_in,
                              void* d_out, int out_size, void* d_ws, size_t ws_size,
                              hipStream_t stream) {
  const int* ev = (const int*)d_in[0];
  const int* parents = (const int*)d_in[1];
  const float* weight = (const float*)d_in[2];
  const float* emb = (const float*)d_in[3];
  const float* gate_w = (const float*)d_in[4];
  const float* gate_b = (const float*)d_in[5];
  float* out = (float*)d_out;

  char* ws = (char*)d_ws;
  float* path = (float*)ws;
  size_t path_bytes = (size_t)NV * NH * sizeof(float);
  float* hbuf = (float*)(ws + path_bytes);
  int* flags = (int*)(ws + path_bytes + (size_t)2 * NB * NH * sizeof(float));

  init_kernel<<<(2 * NB * NH + 255) / 256, 256, 0, stream>>>(hbuf, flags);
  path_kernel<<<NV, 256, 0, stream>>>(parents, weight, emb, path);
  lstm_kernel<<<NGRP * BPG, NTH, 0, stream>>>(ev, path, gate_w, gate_b, hbuf, flags, out);
}

// Round 5
// 14359.882 us; speedup vs baseline: 3.2010x; 3.2010x over previous
//
#include <hip/hip_runtime.h>
#include <math.h>

// Problem constants (fixed by the reference)
#define NV 20000
#define NH 512
#define NT 1024
#define NB 32
#define MAXD 64

// LSTM persistent-kernel geometry
#define NGRP 8      // groups (independent batch-row sets), sync domain = 1 group
#define BPG 32      // blocks per group
#define BPB 4       // batch rows per group  (NB / NGRP)
#define UPB 16      // hidden units per block (NH / BPG)
#define NJ 64       // gate rows per block = 4*UPB
#define KTOT 1024   // 2*NH
#define NTH 512
#define KPT 32      // k elements per thread slice

// ws layout: [ path: NV*NH f32 | hbuf: 2*NB*NH f32 | flags: 256 ints ]  ~= 41.1 MB

// hbuf/flags are communicated via cache-bypass (system-scope) accesses in
// lstm_kernel, so initialize them the same way: zeros must land at the
// coherent point, not sit dirty in one XCD's L2 where bypass loads miss them.
__global__ void init_kernel(float* __restrict__ hbuf, int* __restrict__ flags) {
  int i = blockIdx.x * blockDim.x + threadIdx.x;
  if (i < 2 * NB * NH)
    __hip_atomic_store(&hbuf[i], 0.f, __ATOMIC_RELAXED, __HIP_MEMORY_SCOPE_SYSTEM);
  if (i < 256)
    __hip_atomic_store(&flags[i], 0, __ATOMIC_RELAXED, __HIP_MEMORY_SCOPE_SYSTEM);
}

// One block per node: all 256 threads walk the same parent chain (uniform),
// each thread accumulates 2 of the 512 embedding columns (coalesced).
__global__ __launch_bounds__(256)
void path_kernel(const int* __restrict__ parents,
                 const float* __restrict__ weight,
                 const float* __restrict__ emb,
                 float* __restrict__ path) {
  int v = blockIdx.x;
  int h = threadIdx.x;
  float acc0 = 0.f, acc1 = 0.f;
  float w = 1.f;
  int cur = v;
#pragma unroll 1
  for (int d = 0; d < MAXD; ++d) {
    if (cur < 0) break;
    const float* row = emb + (size_t)cur * NH;
    acc0 = fmaf(w, row[h], acc0);
    acc1 = fmaf(w, row[h + 256], acc1);
    w *= weight[cur];
    cur = parents[cur];
  }
  path[(size_t)v * NH + h] = acc0;
  path[(size_t)v * NH + h + 256] = acc1;
}

// Persistent LSTM: 256 blocks = 8 groups x 32 blocks.
// Cross-block communication (hbuf, flags) uses per-access system-scope
// atomics (sc0 sc1: cache-bypass to the coherent point). NO cache-wide
// fences -> path/gate_w/ev stay L2-resident across steps.
// Producer ordering: wave-0 h-stores -> s_waitcnt vmcnt(0) -> flag add.
// __launch_bounds__(512,2): 128-VGPR budget, w[] stays in regs (R4 lesson:
// without it the compiler caps at 64 VGPRs and spills w to scratch, +68 GB).
__global__ __launch_bounds__(NTH, 2)
void lstm_kernel(const int* __restrict__ ev,
                 const float* __restrict__ path,
                 const float* __restrict__ gate_w,
                 const float* __restrict__ gate_b,
                 float* __restrict__ hbuf,   // [2][NB][NH]
                 int* __restrict__ flags,    // per-group monotonic barrier ctr
                 float* __restrict__ out) {  // [3][NT][NB][NH]
  // in_s padded with one extra float per 32 (f(k)=k+(k>>5)) -> conflict-free
  __shared__ float in_s[BPB][KTOT + KTOT / 32];
  __shared__ float p_s[KPT][NJ * BPB + 1];   // stride 257 -> conflict-free
  __shared__ float zred[NJ * BPB];
  __shared__ float c_s[BPB][UPB];

  const int bid = blockIdx.x;
  const int grp = bid & 7;
  const int blk = bid >> 3;
  const int b0 = grp * BPB;
  const int u0 = blk * UPB;
  const int tid = threadIdx.x;
  const int jg = tid >> 5;   // 0..15: which 4-row group
  const int ks = tid & 31;   // 0..31: which 32-wide k slice

  // Load this thread's gate_w slice into registers (reused for all 1024 steps).
  float w[4][KPT];
#pragma unroll
  for (int jj = 0; jj < 4; ++jj) {
    int r = jg * 4 + jj;                        // 0..63: gate*16 + uu
    int j = (r >> 4) * NH + u0 + (r & 15);      // global gate row
    const float* wr = gate_w + (size_t)j * KTOT + ks * KPT;
#pragma unroll
    for (int kk = 0; kk < KPT; ++kk) w[jj][kk] = wr[kk];
  }

  if (tid < BPB * UPB) c_s[tid >> 4][tid & 15] = 0.f;

  const int sb = tid >> 7;     // staging: batch row
  const int seg = tid & 127;   // staging: 8-float chunk within [x|h]
  const int c0 = seg * 8;
  int* flagp = &flags[grp * 32];
  const size_t plane = (size_t)NT * NB * NH;

  // ---- pre-stage x(0) (path gather), seg<64 covers the x half ----
  if (seg < 64) {
    int e = ev[0 * NB + b0 + sb];
    const float* src = path + (size_t)e * NH + c0;
    float4 v0 = *(const float4*)(src);
    float4 v1 = *(const float4*)(src + 4);
    float* dst = &in_s[sb][0];
    int f0 = c0 + (c0 >> 5);
    dst[f0 + 0] = v0.x; dst[f0 + 1] = v0.y; dst[f0 + 2] = v0.z; dst[f0 + 3] = v0.w;
    dst[f0 + 4] = v1.x; dst[f0 + 5] = v1.y; dst[f0 + 6] = v1.z; dst[f0 + 7] = v1.w;
  }

#pragma unroll 1
  for (int t = 0; t < NT; ++t) {
    const bool more = (t + 1 < NT);

    // ---- stage h(t) for this group's 4 batch rows (coherent bypass loads) --
    if (seg >= 64) {
      const float* hsrc = hbuf + ((size_t)(t & 1) * NB + (b0 + sb)) * NH + (c0 - NH);
      float hv8[8];
#pragma unroll
      for (int q = 0; q < 8; ++q)
        hv8[q] = __hip_atomic_load(hsrc + q, __ATOMIC_RELAXED, __HIP_MEMORY_SCOPE_SYSTEM);
      float* dst = &in_s[sb][0];
      int f0 = c0 + (c0 >> 5);
#pragma unroll
      for (int q = 0; q < 8; ++q) dst[f0 + q] = hv8[q];
    }
    __syncthreads();   // A: in_s(t) complete

    // ---- partial GEMM: acc[jj][bi] over this thread's 32-k slice ----
    float acc[4][BPB];
#pragma unroll
    for (int jj = 0; jj < 4; ++jj)
#pragma unroll
      for (int bi = 0; bi < BPB; ++bi) acc[jj][bi] = 0.f;
    const int fb = ks * (KPT + 1);  // f(ks*32) = ks*33
#pragma unroll
    for (int bi = 0; bi < BPB; ++bi) {
      const float* inp = &in_s[bi][fb];
#pragma unroll
      for (int kk = 0; kk < KPT; ++kk) {
        float x = inp[kk];
        acc[0][bi] = fmaf(w[0][kk], x, acc[0][bi]);
        acc[1][bi] = fmaf(w[1][kk], x, acc[1][bi]);
        acc[2][bi] = fmaf(w[2][kk], x, acc[2][bi]);
        acc[3][bi] = fmaf(w[3][kk], x, acc[3][bi]);
      }
    }
#pragma unroll
    for (int jj = 0; jj < 4; ++jj) {
      int r = jg * 4 + jj;
#pragma unroll
      for (int bi = 0; bi < BPB; ++bi)
        p_s[ks][r * BPB + bi] = acc[jj][bi];
    }
    __syncthreads();   // B: p_s complete; in_s dead

    // ---- prefetch x(t+1) into in_s x-half (barrier-independent) ----
    if (more && seg < 64) {
      int e = ev[(t + 1) * NB + b0 + sb];
      const float* src = path + (size_t)e * NH + c0;
      float4 v0 = *(const float4*)(src);
      float4 v1 = *(const float4*)(src + 4);
      float* dst = &in_s[sb][0];
      int f0 = c0 + (c0 >> 5);
      dst[f0 + 0] = v0.x; dst[f0 + 1] = v0.y; dst[f0 + 2] = v0.z; dst[f0 + 3] = v0.w;
      dst[f0 + 4] = v1.x; dst[f0 + 5] = v1.y; dst[f0 + 6] = v1.z; dst[f0 + 7] = v1.w;
    }

    // ---- reduce k-slices + bias ----
    if (tid < NJ * BPB) {
      float s = 0.f;
#pragma unroll
      for (int k2 = 0; k2 < KPT; ++k2) s += p_s[k2][tid];
      int r = tid >> 2;
      s += gate_b[(r >> 4) * NH + u0 + (r & 15)];
      zred[tid] = s;
    }
    __syncthreads();   // C: zred complete

    // ---- gates + state update (wave 0 only: tid < 64) ----
    float hv = 0.f, cv = 0.f, ogv = 0.f;
    int b = 0, u = 0;
    const bool gate_thread = tid < BPB * UPB;
    if (gate_thread) {
      int bi = tid >> 4, uu = tid & 15;
      float zi = zred[(uu) * BPB + bi];
      float zf = zred[(UPB + uu) * BPB + bi];
      float zg = zred[(2 * UPB + uu) * BPB + bi];
      float zo = zred[(3 * UPB + uu) * BPB + bi];
      float ig = 1.f / (1.f + expf(-zi));
      float fg = 1.f / (1.f + expf(-zf));
      float gg = tanhf(zg);
      ogv = 1.f / (1.f + expf(-zo));
      cv = fmaf(fg, c_s[bi][uu], ig * gg);
      hv = ogv * tanhf(cv);
      c_s[bi][uu] = cv;
      b = b0 + bi; u = u0 + uu;
      if (more) {
        float* hdst = hbuf + ((size_t)((t + 1) & 1) * NB + b) * NH + u;
        __hip_atomic_store(hdst, hv, __ATOMIC_RELAXED, __HIP_MEMORY_SCOPE_SYSTEM);
      }
    }

    // ---- arrive: wave-local wait for h-store completion, then one add ----
    if (more && tid == 0) {
      asm volatile("s_waitcnt vmcnt(0)" ::: "memory");
      __hip_atomic_fetch_add(flagp, 1, __ATOMIC_RELAXED, __HIP_MEMORY_SCOPE_SYSTEM);
    }

    // ---- output stores overlap the barrier wait window ----
    if (gate_thread) {
      size_t o0 = ((size_t)t * NB + b) * NH + u;
      out[o0] = hv;
      out[plane + o0] = cv;
      out[2 * plane + o0] = ogv;
    }

    // ---- single-lane poll ----
    if (more && tid == 0) {
      const int target = BPG * (t + 1);
      while (__hip_atomic_load(flagp, __ATOMIC_RELAXED, __HIP_MEMORY_SCOPE_SYSTEM) < target)
        __builtin_amdgcn_s_sleep(2);
    }
    __syncthreads();   // E: all waves released; h(t+1) globally visible
  }
}

extern "C" void kernel_launch(void* const* d_in, const int* in_sizes, int n_in,
                              void* d_out, int out_size, void* d_ws, size_t ws_size,
                              hipStream_t stream) {
  const int* ev = (const int*)d_in[0];
  const int* parents = (const int*)d_in[1];
  const float* weight = (const float*)d_in[2];
  const float* emb = (const float*)d_in[3];
  const float* gate_w = (const float*)d_in[4];
  const float* gate_b = (const float*)d_in[5];
  float* out = (float*)d_out;

  char* ws = (char*)d_ws;
  float* path = (float*)ws;
  size_t path_bytes = (size_t)NV * NH * sizeof(float);
  float* hbuf = (float*)(ws + path_bytes);
  int* flags = (int*)(ws + path_bytes + (size_t)2 * NB * NH * sizeof(float));

  init_kernel<<<(2 * NB * NH + 255) / 256, 256, 0, stream>>>(hbuf, flags);
  path_kernel<<<NV, 256, 0, stream>>>(parents, weight, emb, path);
  lstm_kernel<<<NGRP * BPG, NTH, 0, stream>>>(ev, path, gate_w, gate_b, hbuf, flags, out);
}

// Round 7
// 12790.095 us; speedup vs baseline: 3.5938x; 1.1227x over previous
//
#include <hip/hip_runtime.h>
#include <math.h>

// Problem constants (fixed by the reference)
#define NV 20000
#define NH 512
#define NT 1024
#define NB 32
#define MAXD 64

// LSTM persistent-kernel geometry
#define NGRP 8      // groups (independent batch-row sets); sync domain = 1 group
#define BPG 32      // blocks per group
#define BPB 4       // batch rows per group  (NB / NGRP)
#define UPB 16      // hidden units per block (NH / BPG)
#define NJ 64       // gate rows per block = 4*UPB
#define KTOT 1024   // 2*NH
#define NTH 512
#define KHALF 16    // k elements per thread per half (x-half + h-half = 32)

// ws layout: [ path: NV*NH f32 | hbuf: 2*NB*NH f32 | prog: 256 ints ] ~= 41.1 MB

__global__ void init_kernel(float* __restrict__ hbuf, int* __restrict__ prog) {
  int i = blockIdx.x * blockDim.x + threadIdx.x;
  if (i < 2 * NB * NH)
    __hip_atomic_store(&hbuf[i], 0.f, __ATOMIC_RELAXED, __HIP_MEMORY_SCOPE_SYSTEM);
  if (i < 256)
    __hip_atomic_store(&prog[i], 0, __ATOMIC_RELAXED, __HIP_MEMORY_SCOPE_SYSTEM);
}

// One block per node: all 256 threads walk the same parent chain (uniform),
// each thread accumulates 2 of the 512 embedding columns (coalesced).
__global__ __launch_bounds__(256)
void path_kernel(const int* __restrict__ parents,
                 const float* __restrict__ weight,
                 const float* __restrict__ emb,
                 float* __restrict__ path) {
  int v = blockIdx.x;
  int h = threadIdx.x;
  float acc0 = 0.f, acc1 = 0.f;
  float w = 1.f;
  int cur = v;
#pragma unroll 1
  for (int d = 0; d < MAXD; ++d) {
    if (cur < 0) break;
    const float* row = emb + (size_t)cur * NH;
    acc0 = fmaf(w, row[h], acc0);
    acc1 = fmaf(w, row[h + 256], acc1);
    w *= weight[cur];
    cur = parents[cur];
  }
  path[(size_t)v * NH + h] = acc0;
  path[(size_t)v * NH + h + 256] = acc1;
}

// f(k) = k + k/32 : +1 dword pad per 32 -> conflict-free LDS columns
__device__ __forceinline__ int fpad(int k) { return k + (k >> 5); }

// Persistent LSTM: 256 blocks = 8 groups x 32 blocks, 1 block/CU.
// Cross-block data (hbuf, prog) moves via sc0 sc1 cache-bypass accesses
// (coherent point), everything else stays L2-cached. No cache-wide fences.
// Producer: h stores -> s_waitcnt vmcnt(0) -> prog[blk]=t+1 (per-producer
// word, no RMW). Consumer: 32-lane bypass load of the group's prog words +
// __ballot. h x4 bypass load is issued early and hidden under the x-half
// GEMM (async-STAGE split).
__global__ __launch_bounds__(NTH, 1)
void lstm_kernel(const int* __restrict__ ev,
                 const float* __restrict__ path,
                 const float* __restrict__ gate_w,
                 const float* __restrict__ gate_b,
                 float* __restrict__ hbuf,   // [2][NB][NH]
                 int* __restrict__ prog,     // [NGRP][BPG] per-producer step ctr
                 float* __restrict__ out) {  // [3][NT][NB][NH]
  __shared__ float in_s[BPB][KTOT + KTOT / 32];   // [x(t) | h(t)] padded
  __shared__ float p_s[32][NJ * BPB + 1];         // stride 257 -> conflict-free
  __shared__ float zred[NJ * BPB];
  __shared__ float c_s[BPB][UPB];

  const int bid = blockIdx.x;
  const int grp = bid & 7;
  const int blk = bid >> 3;
  const int b0 = grp * BPB;
  const int u0 = blk * UPB;
  const int tid = threadIdx.x;
  const int jg = tid >> 5;   // 0..15: which 4-row group of gate rows
  const int ks = tid & 31;   // 0..31: which k-slice (16 x-k + 16 h-k)

  // gate_w slice in registers for all 1024 steps:
  // w[jj][0..15]  = W[j][ks*16 .. +16)          (x half)
  // w[jj][16..31] = W[j][512 + ks*16 .. +16)    (h half)
  float w[4][2 * KHALF];
#pragma unroll
  for (int jj = 0; jj < 4; ++jj) {
    int r = jg * 4 + jj;                        // 0..63: gate*16 + uu
    int j = (r >> 4) * NH + u0 + (r & 15);      // global gate row
    const float* wx = gate_w + (size_t)j * KTOT + ks * KHALF;
    const float* wh = gate_w + (size_t)j * KTOT + NH + ks * KHALF;
#pragma unroll
    for (int kk = 0; kk < KHALF; ++kk) {
      w[jj][kk] = wx[kk];
      w[jj][KHALF + kk] = wh[kk];
    }
  }

  if (tid < BPB * UPB) c_s[tid >> 4][tid & 15] = 0.f;

  // staging map: thread -> (row sb2, 4-float chunk off4)
  const int sb2 = tid >> 7;          // 0..3
  const int off4 = (tid & 127) * 4;  // 0..508
  const size_t plane = (size_t)NT * NB * NH;
  int* myprog = prog + grp * BPG + blk;
  const int* pollp = prog + grp * BPG + (tid & 31);

  // pre-stage x(0) (cached loads; visibility via barrier A0 at t=0)
  {
    int e = ev[0 * NB + b0 + sb2];
    float4 v0 = *(const float4*)(path + (size_t)e * NH + off4);
    *(float4*)&in_s[sb2][fpad(off4)] = v0;
  }

#pragma unroll 1
  for (int t = 0; t < NT; ++t) {
    const bool more = (t + 1 < NT);

    // ---- wait for group's h(t) producers (t=0: hbuf zeros from init) ----
    if (t > 0 && tid < 64) {
      int pv;
      for (;;) {
        asm volatile("global_load_dword %0, %1, off sc0 sc1\n\ts_waitcnt vmcnt(0)"
                     : "=v"(pv) : "v"(pollp) : "memory");
        if (__ballot(pv >= t) == ~0ull) break;
        __builtin_amdgcn_s_sleep(1);
      }
    }
    __syncthreads();   // A0: poll passed; prev step's LDS reads all complete

    // ---- issue h(t) bypass load (16B/thread), fly under x-half GEMM ----
    float4 hv;
    {
      const float* hsrc =
          hbuf + ((size_t)(t & 1) * NB + (b0 + sb2)) * NH + off4;
      asm volatile("global_load_dwordx4 %0, %1, off sc0 sc1"
                   : "=v"(hv) : "v"(hsrc) : "memory");
    }

    // ---- x-half GEMM: k in [ks*16, ks*16+16) from in_s x-half ----
    float acc[4][BPB];
#pragma unroll
    for (int jj = 0; jj < 4; ++jj)
#pragma unroll
      for (int bi = 0; bi < BPB; ++bi) acc[jj][bi] = 0.f;
    {
      const int fb = fpad(ks * KHALF);
#pragma unroll
      for (int bi = 0; bi < BPB; ++bi) {
        const float* inp = &in_s[bi][fb];
#pragma unroll
        for (int kk = 0; kk < KHALF; ++kk) {
          float x = inp[kk];
          acc[0][bi] = fmaf(w[0][kk], x, acc[0][bi]);
          acc[1][bi] = fmaf(w[1][kk], x, acc[1][bi]);
          acc[2][bi] = fmaf(w[2][kk], x, acc[2][bi]);
          acc[3][bi] = fmaf(w[3][kk], x, acc[3][bi]);
        }
      }
    }

    // ---- h arrived: drain the bypass load, then write to LDS h-half ----
    asm volatile("s_waitcnt vmcnt(0)" ::: "memory");
    __builtin_amdgcn_sched_barrier(0);
    *(float4*)&in_s[sb2][fpad(NH + off4)] = hv;
    __syncthreads();   // A1: h(t) staged

    // ---- h-half GEMM: k in [512 + ks*16, +16) ----
    {
      const int fb = fpad(NH + ks * KHALF);
#pragma unroll
      for (int bi = 0; bi < BPB; ++bi) {
        const float* inp = &in_s[bi][fb];
#pragma unroll
        for (int kk = 0; kk < KHALF; ++kk) {
          float x = inp[kk];
          acc[0][bi] = fmaf(w[0][KHALF + kk], x, acc[0][bi]);
          acc[1][bi] = fmaf(w[1][KHALF + kk], x, acc[1][bi]);
          acc[2][bi] = fmaf(w[2][KHALF + kk], x, acc[2][bi]);
          acc[3][bi] = fmaf(w[3][KHALF + kk], x, acc[3][bi]);
        }
      }
    }
#pragma unroll
    for (int jj = 0; jj < 4; ++jj) {
      int r = jg * 4 + jj;
#pragma unroll
      for (int bi = 0; bi < BPB; ++bi)
        p_s[ks][r * BPB + bi] = acc[jj][bi];
    }
    __syncthreads();   // B: p_s complete; in_s x-half dead

    // ---- prefetch x(t+1) into in_s x-half (cached; off critical path) ----
    if (more) {
      int e = ev[(t + 1) * NB + b0 + sb2];
      float4 v0 = *(const float4*)(path + (size_t)e * NH + off4);
      *(float4*)&in_s[sb2][fpad(off4)] = v0;
    }

    // ---- reduce 32 k-slices + bias ----
    if (tid < NJ * BPB) {
      float s = 0.f;
#pragma unroll
      for (int k2 = 0; k2 < 32; ++k2) s += p_s[k2][tid];
      int r = tid >> 2;
      s += gate_b[(r >> 4) * NH + u0 + (r & 15)];
      zred[tid] = s;
    }
    __syncthreads();   // C: zred complete

    // ---- gates + state update + handoff (wave 0 only) ----
    if (tid < BPB * UPB) {
      int bi = tid >> 4, uu = tid & 15;
      float zi = zred[(uu) * BPB + bi];
      float zf = zred[(UPB + uu) * BPB + bi];
      float zg = zred[(2 * UPB + uu) * BPB + bi];
      float zo = zred[(3 * UPB + uu) * BPB + bi];
      float ig = 1.f / (1.f + expf(-zi));
      float fg = 1.f / (1.f + expf(-zf));
      float gg = tanhf(zg);
      float ogv = 1.f / (1.f + expf(-zo));
      float cv = fmaf(fg, c_s[bi][uu], ig * gg);
      float hvv = ogv * tanhf(cv);
      c_s[bi][uu] = cv;
      int b = b0 + bi, u = u0 + uu;
      if (more) {
        float* hdst = hbuf + ((size_t)((t + 1) & 1) * NB + b) * NH + u;
        __hip_atomic_store(hdst, hvv, __ATOMIC_RELAXED, __HIP_MEMORY_SCOPE_SYSTEM);
      }
      // announce: wave-local drain of the h stores, then per-producer word
      if (more && tid == 0) {
        asm volatile("s_waitcnt vmcnt(0)" ::: "memory");
        int nv = t + 1;
        asm volatile("global_store_dword %0, %1, off sc0 sc1"
                     :: "v"(myprog), "v"(nv) : "memory");
      }
      // output stores off the critical path
      size_t o0 = ((size_t)t * NB + b) * NH + u;
      out[o0] = hvv;
      out[plane + o0] = cv;
      out[2 * plane + o0] = ogv;
    }
    // no end-of-step barrier: next iteration's poll + A0 covers it
  }
}

extern "C" void kernel_launch(void* const* d_in, const int* in_sizes, int n_in,
                              void* d_out, int out_size, void* d_ws, size_t ws_size,
                              hipStream_t stream) {
  const int* ev = (const int*)d_in[0];
  const int* parents = (const int*)d_in[1];
  const float* weight = (const float*)d_in[2];
  const float* emb = (const float*)d_in[3];
  const float* gate_w = (const float*)d_in[4];
  const float* gate_b = (const float*)d_in[5];
  float* out = (float*)d_out;

  char* ws = (char*)d_ws;
  float* path = (float*)ws;
  size_t path_bytes = (size_t)NV * NH * sizeof(float);
  float* hbuf = (float*)(ws + path_bytes);
  int* prog = (int*)(ws + path_bytes + (size_t)2 * NB * NH * sizeof(float));

  init_kernel<<<(2 * NB * NH + 255) / 256, 256, 0, stream>>>(hbuf, prog);
  path_kernel<<<NV, 256, 0, stream>>>(parents, weight, emb, path);
  lstm_kernel<<<NGRP * BPG, NTH, 0, stream>>>(ev, path, gate_w, gate_b, hbuf, prog, out);
}